// Round 8
// baseline (77.567 us; speedup 1.0000x reference)
//
#include <hip/hip_runtime.h>
#include <hip/hip_bf16.h>
#include <stdint.h>

typedef __bf16 bf16x8 __attribute__((ext_vector_type(8)));
typedef float  f32x4  __attribute__((ext_vector_type(4)));

union U16x8 { bf16x8 v; unsigned short s[8]; uint4 q; };

// Schraudolph exp-in-bits: exp(x) ~= as_float((uint)(x*log2e*2^23 + (127-0.0437)*2^23))
// a is folded into the s-projection (k_proj), b into the MFMA accumulator init.
#define SCH_SCALE 12102203.0f      // log2(e) * 2^23
#define SCH_BIAS  1064986823.0f    // (127 - 0.043677) * 2^23

__device__ inline unsigned short f2bf(float f) {
  union { float f; unsigned int u; } x; x.f = f;
  unsigned int r = x.u + 0x7FFFu + ((x.u >> 16) & 1u);
  return (unsigned short)(r >> 16);
}
__device__ inline float bf2f(unsigned short u) {
  union { unsigned int u; float f; } x; x.u = ((unsigned int)u) << 16; return x.f;
}

// ---------------------------------------------------------------- K1: projections -> sT,fT,gT (bf16, [n][c]) + exact Sx partials
// sT is pre-scaled by SCH_SCALE so k_scores' MFMA emits a*F directly.
__global__ __launch_bounds__(256) void k_proj(
    const float* __restrict__ stu, const float* __restrict__ tea,
    const float* __restrict__ si_w, const float* __restrict__ fi_w, const float* __restrict__ gi_w,
    const float* __restrict__ si_b, const float* __restrict__ fi_b, const float* __restrict__ gi_b,
    unsigned short* __restrict__ sT, unsigned short* __restrict__ fT, unsigned short* __restrict__ gT,
    float* __restrict__ Sxp) {
  int bid = blockIdx.x;               // 256 = br_ba(8) * nt(32)
  int br_ba = bid & 7;
  int nt = bid >> 3;
  int br = br_ba >> 2, ba = br_ba & 3;
  const float* x = (br ? tea : stu) + (size_t)ba * 64 * 4096;
  int t = threadIdx.x;
  int wid = t >> 6, l = t & 63, g = l >> 4, lr = l & 15;
  int n0 = nt * 128 + wid * 32;

  U16x8 afr[2][2];
  float sx[2][8];
  #pragma unroll
  for (int kh = 0; kh < 2; ++kh)
    #pragma unroll
    for (int j = 0; j < 8; ++j) sx[kh][j] = 0.f;

  #pragma unroll
  for (int rf = 0; rf < 2; ++rf) {
    int n = n0 + rf * 16 + lr;
    #pragma unroll
    for (int kh = 0; kh < 2; ++kh) {
      #pragma unroll
      for (int j = 0; j < 8; ++j) {
        int c = kh * 32 + g * 8 + j;
        float v = x[(size_t)c * 4096 + n];
        afr[rf][kh].s[j] = f2bf(v);
        sx[kh][j] += v;
      }
    }
  }
  // exact spatial-sum partials: reduce over the 16 lr lanes (rows), collect per c
  #pragma unroll
  for (int kh = 0; kh < 2; ++kh)
    #pragma unroll
    for (int j = 0; j < 8; ++j) {
      float v = sx[kh][j];
      v += __shfl_xor(v, 1); v += __shfl_xor(v, 2);
      v += __shfl_xor(v, 4); v += __shfl_xor(v, 8);
      sx[kh][j] = v;
    }
  __shared__ float sxl[4][64];
  if (lr == 0) {
    #pragma unroll
    for (int kh = 0; kh < 2; ++kh)
      #pragma unroll
      for (int j = 0; j < 8; ++j)
        sxl[wid][kh * 32 + g * 8 + j] = sx[kh][j];
  }
  __syncthreads();
  if (t < 64)
    Sxp[bid * 64 + t] = (sxl[0][t] + sxl[1][t]) + (sxl[2][t] + sxl[3][t]);

  size_t obase = (size_t)br_ba * 4096 * 64;
  auto proj_one = [&](const float* w, const float* bias, float scale, unsigned short* op) {
    U16x8 bfr[4][2];
    #pragma unroll
    for (int cf = 0; cf < 4; ++cf) {
      int d = cf * 16 + lr;
      #pragma unroll
      for (int kh = 0; kh < 2; ++kh) {
        const float* wr = w + d * 64 + kh * 32 + g * 8;
        float4 w0 = *(const float4*)(wr);
        float4 w1 = *(const float4*)(wr + 4);
        bfr[cf][kh].s[0] = f2bf(w0.x * scale); bfr[cf][kh].s[1] = f2bf(w0.y * scale);
        bfr[cf][kh].s[2] = f2bf(w0.z * scale); bfr[cf][kh].s[3] = f2bf(w0.w * scale);
        bfr[cf][kh].s[4] = f2bf(w1.x * scale); bfr[cf][kh].s[5] = f2bf(w1.y * scale);
        bfr[cf][kh].s[6] = f2bf(w1.z * scale); bfr[cf][kh].s[7] = f2bf(w1.w * scale);
      }
    }
    f32x4 acc[2][4];
    #pragma unroll
    for (int rf = 0; rf < 2; ++rf)
      #pragma unroll
      for (int cf = 0; cf < 4; ++cf)
        acc[rf][cf] = (f32x4){0.f, 0.f, 0.f, 0.f};
    #pragma unroll
    for (int kh = 0; kh < 2; ++kh)
      #pragma unroll
      for (int rf = 0; rf < 2; ++rf)
        #pragma unroll
        for (int cf = 0; cf < 4; ++cf)
          acc[rf][cf] = __builtin_amdgcn_mfma_f32_16x16x32_bf16(
              afr[rf][kh].v, bfr[cf][kh].v, acc[rf][cf], 0, 0, 0);
    #pragma unroll
    for (int cf = 0; cf < 4; ++cf) {
      float bias_v = bias[cf * 16 + lr] * scale;
      #pragma unroll
      for (int rf = 0; rf < 2; ++rf) {
        #pragma unroll
        for (int r = 0; r < 4; ++r) {
          int n = n0 + rf * 16 + g * 4 + r;
          op[(size_t)n * 64 + cf * 16 + lr] = f2bf(acc[rf][cf][r] + bias_v);
        }
      }
    }
  };
  proj_one(si_w, si_b, SCH_SCALE, sT + obase);
  proj_one(fi_w, fi_b, 1.0f, fT + obase);
  proj_one(gi_w, gi_b, 1.0f, gT + obase);
}

// ---------------------------------------------------------------- K2: column exp-sums; MFMA emits a*F+b directly
// Depth-2 rotating register prefetch (4 loads in flight), fully unrolled so
// all slot indices are compile-time (rule #20). Epilogue = cvt_u32 + add.
__global__ __launch_bounds__(256) void k_scores(
    const unsigned short* __restrict__ sT, const unsigned short* __restrict__ fT,
    float* __restrict__ stats_w) {
  int bid = blockIdx.x;               // 2048 = br_ba(8) * strip(64) * mq(4)
  int br_ba = bid & 7;                // consecutive bids -> different XCDs
  int rest = bid >> 3;
  int strip = rest & 63;              // 64-column strip
  int mq = rest >> 6;                 // 1024-row slab
  int t = threadIdx.x;
  int wid = t >> 6, l = t & 63, g = l >> 4, lr = l & 15;

  const unsigned short* sp = sT + ((size_t)br_ba * 4096 + strip * 64) * 64;
  const unsigned short* fp = fT + ((size_t)br_ba * 4096 + mq * 1024 + wid * 16) * 64;
  const unsigned short* fpl = fp + lr * 64 + g * 8;   // lane base; slice k at +k*4096, kh at +kh*32

  U16x8 bfr[4][2];
  #pragma unroll
  for (int nf = 0; nf < 4; ++nf)
    #pragma unroll
    for (int kh = 0; kh < 2; ++kh)
      bfr[nf][kh].q = *(const uint4*)(sp + (size_t)(nf * 16 + lr) * 64 + kh * 32 + g * 8);

  f32x4 S4[4];
  #pragma unroll
  for (int nf = 0; nf < 4; ++nf) S4[nf] = (f32x4){0.f, 0.f, 0.f, 0.f};

  U16x8 fsl[3][2];                    // rotation: slices k, k+1, k+2 in flight
  #pragma unroll
  for (int kh = 0; kh < 2; ++kh) {
    fsl[0][kh].q = *(const uint4*)(fpl + 0 * 4096 + kh * 32);
    fsl[1][kh].q = *(const uint4*)(fpl + 1 * 4096 + kh * 32);
  }

  #pragma unroll
  for (int k = 0; k < 16; ++k) {
    const int cs = k % 3;
    const int ps = (k + 2) % 3;
    if (k < 14) {
      #pragma unroll
      for (int kh = 0; kh < 2; ++kh)
        fsl[ps][kh].q = *(const uint4*)(fpl + (size_t)(k + 2) * 4096 + kh * 32);
    }
    f32x4 acc[4];
    #pragma unroll
    for (int nf = 0; nf < 4; ++nf)
      acc[nf] = (f32x4){SCH_BIAS, SCH_BIAS, SCH_BIAS, SCH_BIAS};
    #pragma unroll
    for (int kh = 0; kh < 2; ++kh)
      #pragma unroll
      for (int nf = 0; nf < 4; ++nf)
        acc[nf] = __builtin_amdgcn_mfma_f32_16x16x32_bf16(
            fsl[cs][kh].v, bfr[nf][kh].v, acc[nf], 0, 0, 0);

    #pragma unroll
    for (int nf = 0; nf < 4; ++nf) {
      #pragma unroll
      for (int r = 0; r < 4; ++r) {
        unsigned int u = (unsigned int)acc[nf][r];   // v_cvt_u32_f32 (saturates neg->0)
        S4[nf][r] += __uint_as_float(u);
      }
    }
  }

  // per-thread S4 holds this thread's 4-row partial for col strip*64 + nf*16 + lr;
  // sum across the 4 g-groups (rows), then across waves (row slabs).
  __shared__ float wsh[4][64];
  #pragma unroll
  for (int nf = 0; nf < 4; ++nf) {
    float w = (S4[nf][0] + S4[nf][1]) + (S4[nf][2] + S4[nf][3]);
    w += __shfl_xor(w, 16);
    w += __shfl_xor(w, 32);
    if (g == 0) wsh[wid][nf * 16 + lr] = w;
  }
  __syncthreads();
  if (t < 64) {
    float w = (wsh[0][t] + wsh[1][t]) + (wsh[2][t] + wsh[3][t]);
    stats_w[((size_t)br_ba * 4096 + strip * 64 + t) * 4 + mq] = w;
  }
}

// ---------------------------------------------------------------- K4: row weights + gbar partials + Z partials
__global__ __launch_bounds__(256) void k_gbar(const unsigned short* __restrict__ gT,
                                              const float* __restrict__ stats_w,
                                              float* __restrict__ gbar_part,
                                              float* __restrict__ zpart) {
  int bid = blockIdx.x;               // 512 = br_ba(8) * seg(64)
  int br_ba = bid & 7;
  int seg = bid >> 3;
  int t = threadIdx.x;
  int n0 = seg * 64;

  __shared__ float wlds[64];
  if (t < 64) {
    float4 a = *(const float4*)(stats_w + ((size_t)br_ba * 4096 + n0 + t) * 4);
    float w = (a.x + a.y) + (a.z + a.w);
    float zsum = w;
    zsum += __shfl_xor(zsum, 1);  zsum += __shfl_xor(zsum, 2);
    zsum += __shfl_xor(zsum, 4);  zsum += __shfl_xor(zsum, 8);
    zsum += __shfl_xor(zsum, 16); zsum += __shfl_xor(zsum, 32);
    if (t == 0) zpart[br_ba * 64 + seg] = zsum;
    wlds[t] = w;
  }
  __syncthreads();

  // gbar partial: sum_n w[n] * g[n][c]
  int c = t & 63, part = t >> 6;
  const unsigned short* gp = gT + ((size_t)br_ba * 4096 + n0) * 64;
  float acc = 0.f;
  #pragma unroll 4
  for (int r = 0; r < 16; ++r) {
    int k = part * 16 + r;
    acc += wlds[k] * bf2f(gp[(size_t)k * 64 + c]);
  }
  __shared__ float red[256];
  red[t] = acc; __syncthreads();
  if (t < 64)
    gbar_part[(size_t)(br_ba * 64 + seg) * 64 + c] =
        red[t] + red[t + 64] + red[t + 128] + red[t + 192];
}

// ---------------------------------------------------------------- K5: final loss
__global__ __launch_bounds__(256) void k_loss(const float* __restrict__ Sxp,
                                              const float* __restrict__ gbar_part,
                                              const float* __restrict__ zpart,
                                              const float* __restrict__ fsg_w,
                                              float* __restrict__ out) {
  int t = threadIdx.x;                // 256: ba = t>>6, d = t&63
  int ba = t >> 6, d = t & 63;
  __shared__ float zsh[8];
  if (t < 8) {
    float z = 0.f;
    for (int s2 = 0; s2 < 64; ++s2) z += zpart[t * 64 + s2];
    zsh[t] = z;
  }
  float gs = 0.f, gt_ = 0.f;
  for (int seg = 0; seg < 64; ++seg) {
    gs  += gbar_part[(size_t)((0 + ba) * 64 + seg) * 64 + d];
    gt_ += gbar_part[(size_t)((4 + ba) * 64 + seg) * 64 + d];
  }
  float sxs = 0.f, sxt = 0.f;
  for (int nt = 0; nt < 32; ++nt) {
    sxs += Sxp[(nt * 8 + 0 + ba) * 64 + d];
    sxt += Sxp[(nt * 8 + 4 + ba) * 64 + d];
  }
  __syncthreads();
  __shared__ float gdiff[4][64];
  gdiff[ba][d] = gs / zsh[ba] - gt_ / zsh[4 + ba];
  __syncthreads();
  float dot = 0.f;
  for (int c = 0; c < 64; ++c) dot += fsg_w[d * 64 + c] * gdiff[ba][c];
  float diff = ((sxs - sxt) + dot) * (1.0f / 4096.0f);
  __shared__ float red[256];
  red[t] = diff * diff; __syncthreads();
  for (int s = 128; s > 0; s >>= 1) { if (t < s) red[t] += red[t + s]; __syncthreads(); }
  if (t == 0) {
    float lnon = red[0];
    out[0] = 2e-5f * lnon;            // NON*R*lnon   (= non_loss * B)
    out[1] = 2e-5f * lnon * 0.25f;    // non_loss
  }
}

// ----------------------------------------------------------------
extern "C" void kernel_launch(void* const* d_in, const int* in_sizes, int n_in,
                              void* d_out, int out_size, void* d_ws, size_t ws_size,
                              hipStream_t stream) {
  const float* stu   = (const float*)d_in[0];
  const float* tea   = (const float*)d_in[1];
  const float* si_w  = (const float*)d_in[2];
  const float* si_b  = (const float*)d_in[3];
  const float* fi_w  = (const float*)d_in[4];
  const float* fi_b  = (const float*)d_in[5];
  const float* gi_w  = (const float*)d_in[6];
  const float* gi_b  = (const float*)d_in[7];
  const float* fsg_w = (const float*)d_in[8];
  // fsg_b (d_in[9]) cancels in the stu-tea difference.

  char* ws = (char*)d_ws;
  size_t off = 0;
  auto alloc = [&](size_t bytes) -> void* {
    void* p = ws + off;
    off = (off + bytes + 255) & ~(size_t)255;
    return p;
  };
  unsigned short* sT  = (unsigned short*)alloc((size_t)8 * 4096 * 64 * 2);
  unsigned short* fT  = (unsigned short*)alloc((size_t)8 * 4096 * 64 * 2);
  unsigned short* gT  = (unsigned short*)alloc((size_t)8 * 4096 * 64 * 2);
  float* stats_w      = (float*)alloc((size_t)8 * 4096 * 4 * 4);
  float* Sxp          = (float*)alloc((size_t)256 * 64 * 4);
  float* zpart        = (float*)alloc(512 * 4);
  float* gbar_part    = (float*)alloc((size_t)8 * 64 * 64 * 4);
  float* out          = (float*)d_out;

  k_proj<<<256, 256, 0, stream>>>(stu, tea, si_w, fi_w, gi_w, si_b, fi_b, gi_b, sT, fT, gT, Sxp);
  k_scores<<<2048, 256, 0, stream>>>(sT, fT, stats_w);
  k_gbar<<<512, 256, 0, stream>>>(gT, stats_w, gbar_part, zpart);
  k_loss<<<1, 256, 0, stream>>>(Sxp, gbar_part, zpart, fsg_w, out);
}

// Round 9
// 61.366 us; speedup vs baseline: 1.2640x; 1.2640x over previous
//
#include <hip/hip_runtime.h>
#include <hip/hip_bf16.h>
#include <stdint.h>

typedef __bf16 bf16x8 __attribute__((ext_vector_type(8)));
typedef float  f32x4  __attribute__((ext_vector_type(4)));

union U16x8 { bf16x8 v; unsigned short s[8]; uint4 q; };

// Schraudolph exp-in-bits: exp(x) ~= as_float((uint)(x*log2e*2^23 + (127-0.0437)*2^23))
// a is folded into the s-projection (k_proj), b into the MFMA accumulator init.
#define SCH_SCALE 12102203.0f      // log2(e) * 2^23
#define SCH_BIAS  1064986823.0f    // (127 - 0.043677) * 2^23

__device__ inline unsigned short f2bf(float f) {
  union { float f; unsigned int u; } x; x.f = f;
  unsigned int r = x.u + 0x7FFFu + ((x.u >> 16) & 1u);
  return (unsigned short)(r >> 16);
}
__device__ inline float bf2f(unsigned short u) {
  union { unsigned int u; float f; } x; x.u = ((unsigned int)u) << 16; return x.f;
}

// ---------------------------------------------------------------- K1: projections -> sT,fT,gT (bf16, [n][c]) + exact Sx partials
// sT is pre-scaled by SCH_SCALE so k_scores' MFMA emits a*F directly.
__global__ __launch_bounds__(256) void k_proj(
    const float* __restrict__ stu, const float* __restrict__ tea,
    const float* __restrict__ si_w, const float* __restrict__ fi_w, const float* __restrict__ gi_w,
    const float* __restrict__ si_b, const float* __restrict__ fi_b, const float* __restrict__ gi_b,
    unsigned short* __restrict__ sT, unsigned short* __restrict__ fT, unsigned short* __restrict__ gT,
    float* __restrict__ Sxp) {
  int bid = blockIdx.x;               // 256 = br_ba(8) * nt(32)
  int br_ba = bid & 7;
  int nt = bid >> 3;
  int br = br_ba >> 2, ba = br_ba & 3;
  const float* x = (br ? tea : stu) + (size_t)ba * 64 * 4096;
  int t = threadIdx.x;
  int wid = t >> 6, l = t & 63, g = l >> 4, lr = l & 15;
  int n0 = nt * 128 + wid * 32;

  U16x8 afr[2][2];
  float sx[2][8];
  #pragma unroll
  for (int kh = 0; kh < 2; ++kh)
    #pragma unroll
    for (int j = 0; j < 8; ++j) sx[kh][j] = 0.f;

  #pragma unroll
  for (int rf = 0; rf < 2; ++rf) {
    int n = n0 + rf * 16 + lr;
    #pragma unroll
    for (int kh = 0; kh < 2; ++kh) {
      #pragma unroll
      for (int j = 0; j < 8; ++j) {
        int c = kh * 32 + g * 8 + j;
        float v = x[(size_t)c * 4096 + n];
        afr[rf][kh].s[j] = f2bf(v);
        sx[kh][j] += v;
      }
    }
  }
  // exact spatial-sum partials: reduce over the 16 lr lanes (rows), collect per c
  #pragma unroll
  for (int kh = 0; kh < 2; ++kh)
    #pragma unroll
    for (int j = 0; j < 8; ++j) {
      float v = sx[kh][j];
      v += __shfl_xor(v, 1); v += __shfl_xor(v, 2);
      v += __shfl_xor(v, 4); v += __shfl_xor(v, 8);
      sx[kh][j] = v;
    }
  __shared__ float sxl[4][64];
  if (lr == 0) {
    #pragma unroll
    for (int kh = 0; kh < 2; ++kh)
      #pragma unroll
      for (int j = 0; j < 8; ++j)
        sxl[wid][kh * 32 + g * 8 + j] = sx[kh][j];
  }
  __syncthreads();
  if (t < 64)
    Sxp[bid * 64 + t] = (sxl[0][t] + sxl[1][t]) + (sxl[2][t] + sxl[3][t]);

  size_t obase = (size_t)br_ba * 4096 * 64;
  auto proj_one = [&](const float* w, const float* bias, float scale, unsigned short* op) {
    U16x8 bfr[4][2];
    #pragma unroll
    for (int cf = 0; cf < 4; ++cf) {
      int d = cf * 16 + lr;
      #pragma unroll
      for (int kh = 0; kh < 2; ++kh) {
        const float* wr = w + d * 64 + kh * 32 + g * 8;
        float4 w0 = *(const float4*)(wr);
        float4 w1 = *(const float4*)(wr + 4);
        bfr[cf][kh].s[0] = f2bf(w0.x * scale); bfr[cf][kh].s[1] = f2bf(w0.y * scale);
        bfr[cf][kh].s[2] = f2bf(w0.z * scale); bfr[cf][kh].s[3] = f2bf(w0.w * scale);
        bfr[cf][kh].s[4] = f2bf(w1.x * scale); bfr[cf][kh].s[5] = f2bf(w1.y * scale);
        bfr[cf][kh].s[6] = f2bf(w1.z * scale); bfr[cf][kh].s[7] = f2bf(w1.w * scale);
      }
    }
    f32x4 acc[2][4];
    #pragma unroll
    for (int rf = 0; rf < 2; ++rf)
      #pragma unroll
      for (int cf = 0; cf < 4; ++cf)
        acc[rf][cf] = (f32x4){0.f, 0.f, 0.f, 0.f};
    #pragma unroll
    for (int kh = 0; kh < 2; ++kh)
      #pragma unroll
      for (int rf = 0; rf < 2; ++rf)
        #pragma unroll
        for (int cf = 0; cf < 4; ++cf)
          acc[rf][cf] = __builtin_amdgcn_mfma_f32_16x16x32_bf16(
              afr[rf][kh].v, bfr[cf][kh].v, acc[rf][cf], 0, 0, 0);
    #pragma unroll
    for (int cf = 0; cf < 4; ++cf) {
      float bias_v = bias[cf * 16 + lr] * scale;
      #pragma unroll
      for (int rf = 0; rf < 2; ++rf) {
        #pragma unroll
        for (int r = 0; r < 4; ++r) {
          int n = n0 + rf * 16 + g * 4 + r;
          op[(size_t)n * 64 + cf * 16 + lr] = f2bf(acc[rf][cf][r] + bias_v);
        }
      }
    }
  };
  proj_one(si_w, si_b, SCH_SCALE, sT + obase);
  proj_one(fi_w, fi_b, 1.0f, fT + obase);
  proj_one(gi_w, gi_b, 1.0f, gT + obase);
}

// ---------------------------------------------------------------- K2: column exp-sums; MFMA emits a*F+b directly
// Block = 256 cols x 512 rows. All 4 waves read the SAME 16-row f-slice
// (one L2->L1 fill, broadcast), each wave owns 64 distinct columns.
// Depth-1 register prefetch; epilogue = cvt_u32 + add (Schraudolph in MFMA).
__global__ __launch_bounds__(256) void k_scores(
    const unsigned short* __restrict__ sT, const unsigned short* __restrict__ fT,
    float* __restrict__ stats_w) {
  int bid = blockIdx.x;               // 1024 = br_ba(8) * cg(16) * rg(8)
  int br_ba = bid & 7;                // consecutive bids -> different XCDs
  int rest = bid >> 3;
  int cg = rest & 15;                 // 256-column group
  int rg = rest >> 4;                 // 512-row group
  int t = threadIdx.x;
  int wid = t >> 6, l = t & 63, g = l >> 4, lr = l & 15;

  const unsigned short* sp = sT + ((size_t)br_ba * 4096 + cg * 256 + wid * 64) * 64;
  const unsigned short* fp = fT + ((size_t)br_ba * 4096 + rg * 512) * 64;  // shared by all waves
  const unsigned short* fpl = fp + lr * 64 + g * 8;   // lane base; slice k at +k*1024

  U16x8 bfr[4][2];
  #pragma unroll
  for (int nf = 0; nf < 4; ++nf)
    #pragma unroll
    for (int kh = 0; kh < 2; ++kh)
      bfr[nf][kh].q = *(const uint4*)(sp + (size_t)(nf * 16 + lr) * 64 + kh * 32 + g * 8);

  f32x4 S4[4];
  #pragma unroll
  for (int nf = 0; nf < 4; ++nf) S4[nf] = (f32x4){0.f, 0.f, 0.f, 0.f};

  U16x8 cur[2], nxt[2];
  #pragma unroll
  for (int kh = 0; kh < 2; ++kh)
    cur[kh].q = *(const uint4*)(fpl + kh * 32);

  #pragma unroll 2
  for (int k = 0; k < 32; ++k) {
    if (k < 31) {
      #pragma unroll
      for (int kh = 0; kh < 2; ++kh)
        nxt[kh].q = *(const uint4*)(fpl + (size_t)(k + 1) * 1024 + kh * 32);
    }
    f32x4 acc[4];
    #pragma unroll
    for (int nf = 0; nf < 4; ++nf)
      acc[nf] = (f32x4){SCH_BIAS, SCH_BIAS, SCH_BIAS, SCH_BIAS};
    #pragma unroll
    for (int kh = 0; kh < 2; ++kh)
      #pragma unroll
      for (int nf = 0; nf < 4; ++nf)
        acc[nf] = __builtin_amdgcn_mfma_f32_16x16x32_bf16(
            cur[kh].v, bfr[nf][kh].v, acc[nf], 0, 0, 0);

    #pragma unroll
    for (int nf = 0; nf < 4; ++nf) {
      #pragma unroll
      for (int r = 0; r < 4; ++r) {
        unsigned int u = (unsigned int)acc[nf][r];   // v_cvt_u32_f32 (saturates neg->0)
        S4[nf][r] += __uint_as_float(u);
      }
    }
    cur[0] = nxt[0];
    cur[1] = nxt[1];
  }

  // per-thread S4: 4-row subset (g-group) of this block's 512 rows, one column.
  // reduce across the 4 g-groups (same column); waves own distinct columns.
  #pragma unroll
  for (int nf = 0; nf < 4; ++nf) {
    float w = (S4[nf][0] + S4[nf][1]) + (S4[nf][2] + S4[nf][3]);
    w += __shfl_xor(w, 16);
    w += __shfl_xor(w, 32);
    if (g == 0) {
      int col = cg * 256 + wid * 64 + nf * 16 + lr;
      stats_w[((size_t)br_ba * 4096 + col) * 8 + rg] = w;
    }
  }
}

// ---------------------------------------------------------------- K4: row weights + gbar partials + Z partials
__global__ __launch_bounds__(256) void k_gbar(const unsigned short* __restrict__ gT,
                                              const float* __restrict__ stats_w,
                                              float* __restrict__ gbar_part,
                                              float* __restrict__ zpart) {
  int bid = blockIdx.x;               // 512 = br_ba(8) * seg(64)
  int br_ba = bid & 7;
  int seg = bid >> 3;
  int t = threadIdx.x;
  int n0 = seg * 64;

  __shared__ float wlds[64];
  if (t < 64) {
    const float4* p = (const float4*)(stats_w + ((size_t)br_ba * 4096 + n0 + t) * 8);
    float4 a = p[0], b = p[1];
    float w = ((a.x + a.y) + (a.z + a.w)) + ((b.x + b.y) + (b.z + b.w));
    float zsum = w;
    zsum += __shfl_xor(zsum, 1);  zsum += __shfl_xor(zsum, 2);
    zsum += __shfl_xor(zsum, 4);  zsum += __shfl_xor(zsum, 8);
    zsum += __shfl_xor(zsum, 16); zsum += __shfl_xor(zsum, 32);
    if (t == 0) zpart[br_ba * 64 + seg] = zsum;
    wlds[t] = w;
  }
  __syncthreads();

  // gbar partial: sum_n w[n] * g[n][c]
  int c = t & 63, part = t >> 6;
  const unsigned short* gp = gT + ((size_t)br_ba * 4096 + n0) * 64;
  float acc = 0.f;
  #pragma unroll 4
  for (int r = 0; r < 16; ++r) {
    int k = part * 16 + r;
    acc += wlds[k] * bf2f(gp[(size_t)k * 64 + c]);
  }
  __shared__ float red[256];
  red[t] = acc; __syncthreads();
  if (t < 64)
    gbar_part[(size_t)(br_ba * 64 + seg) * 64 + c] =
        red[t] + red[t + 64] + red[t + 128] + red[t + 192];
}

// ---------------------------------------------------------------- K5: final loss
__global__ __launch_bounds__(256) void k_loss(const float* __restrict__ Sxp,
                                              const float* __restrict__ gbar_part,
                                              const float* __restrict__ zpart,
                                              const float* __restrict__ fsg_w,
                                              float* __restrict__ out) {
  int t = threadIdx.x;                // 256: ba = t>>6, d = t&63
  int ba = t >> 6, d = t & 63;
  __shared__ float zsh[8];
  if (t < 8) {
    float z = 0.f;
    for (int s2 = 0; s2 < 64; ++s2) z += zpart[t * 64 + s2];
    zsh[t] = z;
  }
  float gs = 0.f, gt_ = 0.f;
  for (int seg = 0; seg < 64; ++seg) {
    gs  += gbar_part[(size_t)((0 + ba) * 64 + seg) * 64 + d];
    gt_ += gbar_part[(size_t)((4 + ba) * 64 + seg) * 64 + d];
  }
  float sxs = 0.f, sxt = 0.f;
  for (int nt = 0; nt < 32; ++nt) {
    sxs += Sxp[(nt * 8 + 0 + ba) * 64 + d];
    sxt += Sxp[(nt * 8 + 4 + ba) * 64 + d];
  }
  __syncthreads();
  __shared__ float gdiff[4][64];
  gdiff[ba][d] = gs / zsh[ba] - gt_ / zsh[4 + ba];
  __syncthreads();
  float dot = 0.f;
  for (int c = 0; c < 64; ++c) dot += fsg_w[d * 64 + c] * gdiff[ba][c];
  float diff = ((sxs - sxt) + dot) * (1.0f / 4096.0f);
  __shared__ float red[256];
  red[t] = diff * diff; __syncthreads();
  for (int s = 128; s > 0; s >>= 1) { if (t < s) red[t] += red[t + s]; __syncthreads(); }
  if (t == 0) {
    float lnon = red[0];
    out[0] = 2e-5f * lnon;            // NON*R*lnon   (= non_loss * B)
    out[1] = 2e-5f * lnon * 0.25f;    // non_loss
  }
}

// ----------------------------------------------------------------
extern "C" void kernel_launch(void* const* d_in, const int* in_sizes, int n_in,
                              void* d_out, int out_size, void* d_ws, size_t ws_size,
                              hipStream_t stream) {
  const float* stu   = (const float*)d_in[0];
  const float* tea   = (const float*)d_in[1];
  const float* si_w  = (const float*)d_in[2];
  const float* si_b  = (const float*)d_in[3];
  const float* fi_w  = (const float*)d_in[4];
  const float* fi_b  = (const float*)d_in[5];
  const float* gi_w  = (const float*)d_in[6];
  const float* gi_b  = (const float*)d_in[7];
  const float* fsg_w = (const float*)d_in[8];
  // fsg_b (d_in[9]) cancels in the stu-tea difference.

  char* ws = (char*)d_ws;
  size_t off = 0;
  auto alloc = [&](size_t bytes) -> void* {
    void* p = ws + off;
    off = (off + bytes + 255) & ~(size_t)255;
    return p;
  };
  unsigned short* sT  = (unsigned short*)alloc((size_t)8 * 4096 * 64 * 2);
  unsigned short* fT  = (unsigned short*)alloc((size_t)8 * 4096 * 64 * 2);
  unsigned short* gT  = (unsigned short*)alloc((size_t)8 * 4096 * 64 * 2);
  float* stats_w      = (float*)alloc((size_t)8 * 4096 * 8 * 4);
  float* Sxp          = (float*)alloc((size_t)256 * 64 * 4);
  float* zpart        = (float*)alloc(512 * 4);
  float* gbar_part    = (float*)alloc((size_t)8 * 64 * 64 * 4);
  float* out          = (float*)d_out;

  k_proj<<<256, 256, 0, stream>>>(stu, tea, si_w, fi_w, gi_w, si_b, fi_b, gi_b, sT, fT, gT, Sxp);
  k_scores<<<1024, 256, 0, stream>>>(sT, fT, stats_w);
  k_gbar<<<512, 256, 0, stream>>>(gT, stats_w, gbar_part, zpart);
  k_loss<<<1, 256, 0, stream>>>(Sxp, gbar_part, zpart, fsg_w, out);
}